// Round 7
// baseline (14347.321 us; speedup 1.0000x reference)
//
#include <hip/hip_runtime.h>

// DA-RNN persistent kernel, round 9: u1v register residency, unlocked via the
// LDS-occupancy trick. R4/R5/R6 all pinned at VGPR=64 because 64KB LDS lets 2
// blocks/CU fit -> allocator targets 8 waves/SIMD and spills u1v. But grid=256
// on 256 CUs is 1 block/CU at runtime anyway. This round: 96KB DYNAMIC LDS
// (64KB used) -> only 1 block/CU fits -> occupancy ceiling 4 waves/SIMD ->
// 128-VGPR budget -> u1v (64 VGPRs of encoder uexT) stays in registers.
// Kills the 8.4 GB uexT re-read stream (dur tracks L2-miss bytes at 1.4 TB/s).
// Math identical to R5 (passed correctness, absmax 9.8e-4).

#define B_   1024
#define T_   128     // T_ENCO
#define NI_  128     // N_INP
#define H_   256     // N_HID
#define H4_  1024    // 4*N_HID
#define TD_  24      // T_DECO
#define DS_  30      // decoder steps
#define BB   4       // batch rows per workgroup
#define TB   1024    // threads per block
#define LDS_BYTES 98304u   // 96 KiB: force 1 block/CU so allocator allows 128 VGPRs

typedef _Float16 hf_t;
typedef _Float16 half8  __attribute__((ext_vector_type(8)));
typedef _Float16 half2v __attribute__((ext_vector_type(2)));

__device__ __forceinline__ float sigm(float x) {
    return __builtin_amdgcn_rcpf(1.0f + __expf(-x));
}
__device__ __forceinline__ float tanh_f(float x) {
    float e = __expf(2.0f * x);
    return 1.0f - 2.0f * __builtin_amdgcn_rcpf(e + 1.0f);
}
__device__ __forceinline__ float fdot2f(half2v a, half2v b, float c) {
#if __has_builtin(__builtin_amdgcn_fdot2)
    return __builtin_amdgcn_fdot2(a, b, c, false);
#else
    return fmaf((float)a.x, (float)b.x, fmaf((float)a.y, (float)b.y, c));
#endif
}
__device__ __forceinline__ float dot8h(half8 w, half8 x, float acc) {
    acc = fdot2f(__builtin_shufflevector(w, w, 0, 1), __builtin_shufflevector(x, x, 0, 1), acc);
    acc = fdot2f(__builtin_shufflevector(w, w, 2, 3), __builtin_shufflevector(x, x, 2, 3), acc);
    acc = fdot2f(__builtin_shufflevector(w, w, 4, 5), __builtin_shufflevector(x, x, 4, 5), acc);
    acc = fdot2f(__builtin_shufflevector(w, w, 6, 7), __builtin_shufflevector(x, x, 6, 7), acc);
    return acc;
}
__device__ __forceinline__ hf_t nt_load_h(const hf_t* p) {
#if __has_builtin(__builtin_nontemporal_load)
    return __builtin_nontemporal_load(p);
#else
    return *p;
#endif
}
__device__ __forceinline__ void nt_store_h(hf_t v, hf_t* p) {
#if __has_builtin(__builtin_nontemporal_store)
    __builtin_nontemporal_store(v, p);
#else
    *p = v;
#endif
}

// ---- f16 weight layout inside d_ws (offsets in halves) ----
#define W_WE    0u
#define W_UE2   131072u
#define W_EWIH  163840u
#define W_EWHH  294912u
#define W_MWIH  557056u
#define W_MWHH  819200u
#define W_DWIH  1081344u
#define W_DWHH  1343488u
#define W_WD    1605632u
#define W_UD    1736704u
#define SCR_A   2097152u       // udmT [b][o][t]  (decoder only now)
#define SCR_B   35651584u      // midb [b][t][k]

__global__ void convw_kernel(const float* __restrict__ sWE, const float* __restrict__ sUE2,
                             const float* __restrict__ sEI, const float* __restrict__ sEH,
                             const float* __restrict__ sMI, const float* __restrict__ sMH,
                             const float* __restrict__ sDI, const float* __restrict__ sDH,
                             const float* __restrict__ sWD, const float* __restrict__ sUD,
                             hf_t* __restrict__ dst) {
    const int gtid = blockIdx.x * blockDim.x + threadIdx.x;
    const int gs   = gridDim.x * blockDim.x;
    for (int n = gtid; n < 131072; n += gs) {       // WE'
        int e = n & 7, q = n >> 3, k = q & 255, c = q >> 8, kq = c >> 4, i = c & 15;
        dst[W_WE + n] = (hf_t)sWE[k * 512 + kq * 128 + i * 8 + e];
    }
    for (int n = gtid; n < 32768; n += gs) {        // UE2'
        int e = n & 7, q = n >> 3, k = q & 255, c = q >> 8, kq = c >> 2, i = c & 3;
        dst[W_UE2 + n] = (hf_t)sUE2[k * 128 + kq * 32 + i * 8 + e];
    }
    for (int n = gtid; n < 131072; n += gs) {       // EWIH' (K=128)
        int e = n & 7, q = n >> 3, o = q & 1023, i = q >> 10;
        dst[W_EWIH + n] = (hf_t)sEI[o * 128 + i * 8 + e];
    }
    for (int n = gtid; n < 262144; n += gs) {       // K=256 gates
        int e = n & 7, q = n >> 3, o = q & 1023, i = q >> 10;
        int s = o * 256 + i * 8 + e;
        dst[W_EWHH + n] = (hf_t)sEH[s];
        dst[W_MWIH + n] = (hf_t)sMI[s];
        dst[W_MWHH + n] = (hf_t)sMH[s];
        dst[W_DWIH + n] = (hf_t)sDI[s];
        dst[W_DWHH + n] = (hf_t)sDH[s];
    }
    for (int n = gtid; n < 131072; n += gs) {       // WD'
        int e = n & 7, q = n >> 3, k = q & 255, c = q >> 8, kq = c >> 4, i = c & 15;
        dst[W_WD + n] = (hf_t)sWD[k * 512 + kq * 128 + i * 8 + e];
    }
    for (int n = gtid; n < 65536; n += gs)          // UD plain
        dst[W_UD + n] = (hf_t)sUD[n];
}

// ---- LDS offsets (floats) ----
#define O_HC    0        // hf [4][512]
#define O_CF    1024     // f32 [4][256]
#define O_HM    2048     // hf [4][256]
#define O_CMF   2560     // f32 [4][256]
#define O_XRAW  3584     // f32 [4][128]
#define O_XH    4096     // hf [4][128]
#define O_XG    4352     // hf [4][128]
#define O_HCXI  4608     // f32 [4][256]
#define O_SPART 5632     // f32 [1024]
#define O_SBUF  6656     // f32 [4][128]
#define O_GBUF  7168     // f32 [4096] (partials / gates / enc score parts)
#define O_DINH  11264    // hf [4][256]
#define O_HF    11776    // f32 [4][256]
#define O_VES   12800    // f32 [256]
#define O_VDS   13056    // f32 [256]

__global__ __launch_bounds__(TB, 4)
__attribute__((amdgpu_waves_per_eu(4, 4)))
void dsrnn_kernel(
    const float* __restrict__ inp,
    const float* __restrict__ UeW,  const float* __restrict__ Ueb,
    const float* __restrict__ Ue2b,
    const float* __restrict__ Web,
    const float* __restrict__ VeW,  const float* __restrict__ Veb,
    const float* __restrict__ Udb,
    const float* __restrict__ Wdb,
    const float* __restrict__ VdW,  const float* __restrict__ Vdb,
    const float* __restrict__ ebih, const float* __restrict__ ebhh,
    const float* __restrict__ mbih, const float* __restrict__ mbhh,
    const float* __restrict__ dbih, const float* __restrict__ dbhh,
    const float* __restrict__ rW,   const float* __restrict__ rb,
    const hf_t* __restrict__ wb,
    hf_t* __restrict__ scrA,
    hf_t* __restrict__ scrB,
    float* __restrict__ out)
{
    extern __shared__ float sm[];
    const int tid = threadIdx.x;
    const int b0  = blockIdx.x * BB;

    hf_t*  hc   = (hf_t*)(sm + O_HC);
    float* cf   = sm + O_CF;
    hf_t*  hm   = (hf_t*)(sm + O_HM);
    float* cmf  = sm + O_CMF;
    float* xraw = sm + O_XRAW;
    hf_t*  xh   = (hf_t*)(sm + O_XH);
    hf_t*  xg   = (hf_t*)(sm + O_XG);
    float* hcxi = sm + O_HCXI;
    float* spart= sm + O_SPART;
    float* sbuf = sm + O_SBUF;
    float* gbuf = sm + O_GBUF;
    hf_t*  dinh = (hf_t*)(sm + O_DINH);
    float* hful = sm + O_HF;
    float* ves  = sm + O_VES;
    float* vds  = sm + O_VDS;

    // ---------- Phase 0: uexT in REGISTERS (64 VGPRs) ----------
    // u1v[b*4+idx][e] = uex[b][k][j], k = kg*32 + idx*8 + e, j = tid&127.
    // Exactly the k-slice the encoder score phase consumes. Never stored.
    half8 u1v[16];
    {
        const int j = tid & 127, kg = tid >> 7;
#pragma unroll
        for (int b = 0; b < BB; ++b) {
            __syncthreads();
            const float* Xg = inp + (size_t)(b0 + b) * T_ * NI_;
            for (int i = tid; i < T_ * NI_; i += TB) sm[i] = Xg[i];
            __syncthreads();
#pragma unroll
            for (int idx = 0; idx < 4; ++idx) {
                half8 v;
#pragma unroll
                for (int e = 0; e < 8; ++e) {
                    const int k = (kg << 5) + idx * 8 + e;
                    const float* wrow = UeW + (size_t)k * T_;
                    float acc = Ueb[k];
#pragma unroll 4
                    for (int t = 0; t < T_; ++t) acc = fmaf(wrow[t], sm[t * NI_ + j], acc);
                    v[e] = (hf_t)acc;
                }
                u1v[b * 4 + idx] = v;
            }
        }
    }
    __syncthreads();
    for (int i = tid; i < 3584; i += TB) sm[i] = 0.0f;   // zero h/c enc+mid
    if (tid < 256) { ves[tid] = VeW[tid]; vds[tid] = VdW[tid]; }
    __syncthreads();

    // ---------- Fused encoder + mid loop ----------
    for (int t = 0; t < T_; ++t) {
        // (a) load x_t
        if (tid < 512) {
            const int b = tid >> 7, j = tid & 127;
            float v = inp[((size_t)(b0 + b) * T_ + t) * NI_ + j];
            xraw[b * NI_ + j] = v;
            xh[b * NI_ + j]   = (hf_t)v;
        }
        __syncthreads();

        // (b) We.[h;c] + Ue2.x partials, k-quarter split
        {
            const int k = tid & 255, kq = tid >> 8;
            const half8* wWE = (const half8*)(wb + W_WE)  + (size_t)(kq * 16) * 256 + k;
            const half8* wU2 = (const half8*)(wb + W_UE2) + (size_t)(kq * 4)  * 256 + k;
            float a0 = 0.f, a1 = 0.f, a2 = 0.f, a3 = 0.f;
#pragma unroll 8
            for (int i = 0; i < 16; ++i) {
                half8 w = wWE[(size_t)i * 256];
                a0 = dot8h(w, *(const half8*)&hc[0 * 512 + kq * 128 + i * 8], a0);
                a1 = dot8h(w, *(const half8*)&hc[1 * 512 + kq * 128 + i * 8], a1);
                a2 = dot8h(w, *(const half8*)&hc[2 * 512 + kq * 128 + i * 8], a2);
                a3 = dot8h(w, *(const half8*)&hc[3 * 512 + kq * 128 + i * 8], a3);
            }
#pragma unroll
            for (int i = 0; i < 4; ++i) {
                half8 w = wU2[(size_t)i * 256];
                a0 = dot8h(w, *(const half8*)&xh[0 * 128 + kq * 32 + i * 8], a0);
                a1 = dot8h(w, *(const half8*)&xh[1 * 128 + kq * 32 + i * 8], a1);
                a2 = dot8h(w, *(const half8*)&xh[2 * 128 + kq * 32 + i * 8], a2);
                a3 = dot8h(w, *(const half8*)&xh[3 * 128 + kq * 32 + i * 8], a3);
            }
            gbuf[kq * 1024 + 0 * 256 + k] = a0;
            gbuf[kq * 1024 + 1 * 256 + k] = a1;
            gbuf[kq * 1024 + 2 * 256 + k] = a2;
            gbuf[kq * 1024 + 3 * 256 + k] = a3;
        }
        __syncthreads();
        {
            const int b = tid >> 8, k = tid & 255;
            hcxi[b * 256 + k] = gbuf[b * 256 + k] + gbuf[1024 + b * 256 + k]
                              + gbuf[2048 + b * 256 + k] + gbuf[3072 + b * 256 + k]
                              + Web[k] + Ue2b[k];
        }
        __syncthreads();

        // (c) scores from u1v registers (Veb dropped: softmax shift-invariant)
        {
            const int j = tid & 127, kg = tid >> 7;
#pragma unroll
            for (int b = 0; b < BB; ++b) {
                float a = 0.f;
#pragma unroll
                for (int idx = 0; idx < 4; ++idx) {
#pragma unroll
                    for (int e = 0; e < 8; ++e) {
                        const int k = (kg << 5) + idx * 8 + e;
                        a = fmaf(ves[k], tanh_f(hcxi[b * 256 + k] + (float)u1v[b * 4 + idx][e]), a);
                    }
                }
                gbuf[(b * 8 + kg) * 128 + j] = a;
            }
        }
        __syncthreads();

        // (d) softmax per b (one wave per b), gate x
        if (tid < 256) {
            const int b = tid >> 6, lane = tid & 63;
            float sA = 0.f, sB = 0.f;
#pragma unroll
            for (int kg = 0; kg < 8; ++kg) {
                sA += gbuf[(b * 8 + kg) * 128 + lane];
                sB += gbuf[(b * 8 + kg) * 128 + lane + 64];
            }
            float m = fmaxf(sA, sB);
            for (int d = 1; d < 64; d <<= 1) m = fmaxf(m, __shfl_xor(m, d));
            float eA = __expf(sA - m), eB = __expf(sB - m);
            float ssum = eA + eB;
            for (int d = 1; d < 64; d <<= 1) ssum += __shfl_xor(ssum, d);
            float inv = 1.0f / ssum;
            xg[b * NI_ + lane]      = (hf_t)(xraw[b * NI_ + lane] * eA * inv);
            xg[b * NI_ + lane + 64] = (hf_t)(xraw[b * NI_ + lane + 64] * eB * inv);
        }
        __syncthreads();

        // (e) encoder gates: thread o owns row o (read exactly once)
        {
            const int o = tid;
            const half8* wih = (const half8*)(wb + W_EWIH) + o;
            const half8* whh = (const half8*)(wb + W_EWHH) + o;
            float bias = ebih[o] + ebhh[o];
            float a0 = bias, a1 = bias, a2 = bias, a3 = bias;
#pragma unroll 8
            for (int i = 0; i < 16; ++i) {
                half8 w = wih[(size_t)i * 1024];
                a0 = dot8h(w, *(const half8*)&xg[0 * 128 + i * 8], a0);
                a1 = dot8h(w, *(const half8*)&xg[1 * 128 + i * 8], a1);
                a2 = dot8h(w, *(const half8*)&xg[2 * 128 + i * 8], a2);
                a3 = dot8h(w, *(const half8*)&xg[3 * 128 + i * 8], a3);
            }
#pragma unroll 8
            for (int i = 0; i < 32; ++i) {
                half8 w = whh[(size_t)i * 1024];
                a0 = dot8h(w, *(const half8*)&hc[0 * 512 + i * 8], a0);
                a1 = dot8h(w, *(const half8*)&hc[1 * 512 + i * 8], a1);
                a2 = dot8h(w, *(const half8*)&hc[2 * 512 + i * 8], a2);
                a3 = dot8h(w, *(const half8*)&hc[3 * 512 + i * 8], a3);
            }
            gbuf[0 * 1024 + o] = a0; gbuf[1 * 1024 + o] = a1;
            gbuf[2 * 1024 + o] = a2; gbuf[3 * 1024 + o] = a3;
        }
        __syncthreads();

        // (f) encoder LSTM update
        {
            const int b = tid >> 8, k = tid & 255;
            float gi = gbuf[b * H4_ + k];
            float gf = gbuf[b * H4_ + H_ + k];
            float gg = gbuf[b * H4_ + 2 * H_ + k];
            float go = gbuf[b * H4_ + 3 * H_ + k];
            float c2 = sigm(gf) * cf[b * H_ + k] + sigm(gi) * tanh_f(gg);
            float h2 = sigm(go) * tanh_f(c2);
            cf[b * H_ + k] = c2;
            hc[b * 512 + k]       = (hf_t)h2;
            hc[b * 512 + 256 + k] = (hf_t)c2;
        }
        __syncthreads();

        // (g) mid gates
        {
            const int o = tid;
            const half8* wih = (const half8*)(wb + W_MWIH) + o;
            const half8* whh = (const half8*)(wb + W_MWHH) + o;
            float bias = mbih[o] + mbhh[o];
            float a0 = bias, a1 = bias, a2 = bias, a3 = bias;
#pragma unroll 8
            for (int i = 0; i < 32; ++i) {
                half8 w = wih[(size_t)i * 1024];
                a0 = dot8h(w, *(const half8*)&hc[0 * 512 + i * 8], a0);
                a1 = dot8h(w, *(const half8*)&hc[1 * 512 + i * 8], a1);
                a2 = dot8h(w, *(const half8*)&hc[2 * 512 + i * 8], a2);
                a3 = dot8h(w, *(const half8*)&hc[3 * 512 + i * 8], a3);
            }
#pragma unroll 8
            for (int i = 0; i < 32; ++i) {
                half8 w = whh[(size_t)i * 1024];
                a0 = dot8h(w, *(const half8*)&hm[0 * 256 + i * 8], a0);
                a1 = dot8h(w, *(const half8*)&hm[1 * 256 + i * 8], a1);
                a2 = dot8h(w, *(const half8*)&hm[2 * 256 + i * 8], a2);
                a3 = dot8h(w, *(const half8*)&hm[3 * 256 + i * 8], a3);
            }
            gbuf[0 * 1024 + o] = a0; gbuf[1 * 1024 + o] = a1;
            gbuf[2 * 1024 + o] = a2; gbuf[3 * 1024 + o] = a3;
        }
        __syncthreads();

        // (h) mid LSTM update + store mid
        {
            const int b = tid >> 8, k = tid & 255;
            float gi = gbuf[b * H4_ + k];
            float gf = gbuf[b * H4_ + H_ + k];
            float gg = gbuf[b * H4_ + 2 * H_ + k];
            float go = gbuf[b * H4_ + 3 * H_ + k];
            float c2 = sigm(gf) * cmf[b * H_ + k] + sigm(gi) * tanh_f(gg);
            float h2 = sigm(go) * tanh_f(c2);
            cmf[b * H_ + k] = c2;
            hm[b * 256 + k] = (hf_t)h2;
            scrB[((size_t)(b0 + b) * T_ + t) * H_ + k] = (hf_t)h2;
        }
        __syncthreads();
    }

    // ---------- udm pass: udmT[b][o][t] = UdW[o,:].mid[b,t,:] + Udb[o] ----------
    {
        const int b = tid >> 8, r = tid & 255, oh = r >> 7, tt = r & 127;
        const half8* mrow = (const half8*)(scrB + ((size_t)(b0 + b) * T_ + tt) * H_);
        half8 m[32];
#pragma unroll
        for (int i = 0; i < 32; ++i) m[i] = mrow[i];
        const half8* udw = (const half8*)(wb + W_UD);
        for (int o2 = 0; o2 < 128; ++o2) {
            const int o = oh * 128 + o2;
            const half8* ur = udw + (size_t)o * 32;
            float acc = Udb[o];
#pragma unroll 8
            for (int i = 0; i < 32; ++i) acc = dot8h(ur[i], m[i], acc);
            nt_store_h((hf_t)acc, scrA + ((size_t)(b0 + b) * 256 + o) * 128 + tt);
        }
    }
    __syncthreads();
    for (int i = tid; i < 2048; i += TB) sm[i] = 0.0f;   // zero dec h/c
    __syncthreads();

    // ---------- Decoder ----------
    for (int s = 0; s < DS_; ++s) {
        // (a') Wd.[h;c] partials, k-quarter split
        {
            const int k = tid & 255, kq = tid >> 8;
            const half8* wWD = (const half8*)(wb + W_WD) + (size_t)(kq * 16) * 256 + k;
            float a0 = 0.f, a1 = 0.f, a2 = 0.f, a3 = 0.f;
#pragma unroll 8
            for (int i = 0; i < 16; ++i) {
                half8 w = wWD[(size_t)i * 256];
                a0 = dot8h(w, *(const half8*)&hc[0 * 512 + kq * 128 + i * 8], a0);
                a1 = dot8h(w, *(const half8*)&hc[1 * 512 + kq * 128 + i * 8], a1);
                a2 = dot8h(w, *(const half8*)&hc[2 * 512 + kq * 128 + i * 8], a2);
                a3 = dot8h(w, *(const half8*)&hc[3 * 512 + kq * 128 + i * 8], a3);
            }
            gbuf[kq * 1024 + 0 * 256 + k] = a0;
            gbuf[kq * 1024 + 1 * 256 + k] = a1;
            gbuf[kq * 1024 + 2 * 256 + k] = a2;
            gbuf[kq * 1024 + 3 * 256 + k] = a3;
        }
        __syncthreads();
        {
            const int b = tid >> 8, k = tid & 255;
            hcxi[b * 256 + k] = gbuf[b * 256 + k] + gbuf[1024 + b * 256 + k]
                              + gbuf[2048 + b * 256 + k] + gbuf[3072 + b * 256 + k]
                              + Wdb[k];
        }
        __syncthreads();

        // (b') temporal scores from udmT (no softmax), nt coalesced loads
        {
            const int b = tid >> 8, r = tid & 255, kh = r >> 7, j = r & 127;
            const hf_t* up = scrA + ((size_t)(b0 + b) * 256 + kh * 128) * 128 + j;
            const float* hx = hcxi + b * 256 + kh * 128;
            const float* vw = vds + kh * 128;
            float acc = kh ? 0.f : Vdb[0];
#pragma unroll 8
            for (int k2 = 0; k2 < 128; ++k2) {
                float u = (float)nt_load_h(up + (size_t)k2 * 128);
                acc = fmaf(vw[k2], tanh_f(hx[k2] + u), acc);
            }
            spart[tid] = acc;
        }
        __syncthreads();
        if (tid < 512) {
            const int b = tid >> 7, j = tid & 127;
            sbuf[b * T_ + j] = spart[(b << 8) + j] + spart[(b << 8) + 128 + j];
        }
        __syncthreads();

        // (d') dec_in[b,h] = sum_j t[b,j] * mid[b,j,h]
        {
            const int b = tid >> 8, h = tid & 255;
            const hf_t* mp = scrB + (size_t)(b0 + b) * T_ * H_ + h;
            float acc = 0.0f;
            for (int j = 0; j < T_; ++j)
                acc = fmaf(sbuf[b * T_ + j], (float)mp[(size_t)j * H_], acc);
            dinh[b * 256 + h] = (hf_t)acc;
        }
        __syncthreads();

        // (e') decoder gates
        {
            const int o = tid;
            const half8* wih = (const half8*)(wb + W_DWIH) + o;
            const half8* whh = (const half8*)(wb + W_DWHH) + o;
            float bias = dbih[o] + dbhh[o];
            float a0 = bias, a1 = bias, a2 = bias, a3 = bias;
#pragma unroll 8
            for (int i = 0; i < 32; ++i) {
                half8 w = wih[(size_t)i * 1024];
                a0 = dot8h(w, *(const half8*)&dinh[0 * 256 + i * 8], a0);
                a1 = dot8h(w, *(const half8*)&dinh[1 * 256 + i * 8], a1);
                a2 = dot8h(w, *(const half8*)&dinh[2 * 256 + i * 8], a2);
                a3 = dot8h(w, *(const half8*)&dinh[3 * 256 + i * 8], a3);
            }
#pragma unroll 8
            for (int i = 0; i < 32; ++i) {
                half8 w = whh[(size_t)i * 1024];
                a0 = dot8h(w, *(const half8*)&hc[0 * 512 + i * 8], a0);
                a1 = dot8h(w, *(const half8*)&hc[1 * 512 + i * 8], a1);
                a2 = dot8h(w, *(const half8*)&hc[2 * 512 + i * 8], a2);
                a3 = dot8h(w, *(const half8*)&hc[3 * 512 + i * 8], a3);
            }
            gbuf[0 * 1024 + o] = a0; gbuf[1 * 1024 + o] = a1;
            gbuf[2 * 1024 + o] = a2; gbuf[3 * 1024 + o] = a3;
        }
        __syncthreads();

        // (f') decoder LSTM update
        {
            const int b = tid >> 8, k = tid & 255;
            float gi = gbuf[b * H4_ + k];
            float gf = gbuf[b * H4_ + H_ + k];
            float gg = gbuf[b * H4_ + 2 * H_ + k];
            float go = gbuf[b * H4_ + 3 * H_ + k];
            float c2 = sigm(gf) * cf[b * H_ + k] + sigm(gi) * tanh_f(gg);
            float h2 = sigm(go) * tanh_f(c2);
            cf[b * H_ + k] = c2;
            hc[b * 512 + k]       = (hf_t)h2;
            hc[b * 512 + 256 + k] = (hf_t)c2;
            hful[b * H_ + k] = h2;
        }
        __syncthreads();

        // (g') out[b, s-6] = rW.h + rb
        if (s >= 6 && tid < 256) {
            const int b = tid >> 6, lane = tid & 63;
            float p = rW[lane]       * hful[b * H_ + lane]
                    + rW[lane + 64]  * hful[b * H_ + lane + 64]
                    + rW[lane + 128] * hful[b * H_ + lane + 128]
                    + rW[lane + 192] * hful[b * H_ + lane + 192];
            for (int d = 1; d < 64; d <<= 1) p += __shfl_xor(p, d);
            if (lane == 0) out[(size_t)(b0 + b) * TD_ + (s - 6)] = p + rb[0];
        }
        __syncthreads();
    }
}

extern "C" void kernel_launch(void* const* d_in, const int* in_sizes, int n_in,
                              void* d_out, int out_size, void* d_ws, size_t ws_size,
                              hipStream_t stream) {
    const float* inp  = (const float*)d_in[0];
    const float* UeW  = (const float*)d_in[2];
    const float* Ueb  = (const float*)d_in[3];
    const float* Ue2W = (const float*)d_in[4];
    const float* Ue2b = (const float*)d_in[5];
    const float* WeW  = (const float*)d_in[6];
    const float* Web  = (const float*)d_in[7];
    const float* VeW  = (const float*)d_in[8];
    const float* Veb  = (const float*)d_in[9];
    const float* UdW  = (const float*)d_in[10];
    const float* Udb  = (const float*)d_in[11];
    const float* WdW  = (const float*)d_in[12];
    const float* Wdb  = (const float*)d_in[13];
    const float* VdW  = (const float*)d_in[14];
    const float* Vdb  = (const float*)d_in[15];
    const float* eWih = (const float*)d_in[16];
    const float* eWhh = (const float*)d_in[17];
    const float* ebih = (const float*)d_in[18];
    const float* ebhh = (const float*)d_in[19];
    const float* mWih = (const float*)d_in[20];
    const float* mWhh = (const float*)d_in[21];
    const float* mbih = (const float*)d_in[22];
    const float* mbhh = (const float*)d_in[23];
    const float* dWih = (const float*)d_in[24];
    const float* dWhh = (const float*)d_in[25];
    const float* dbih = (const float*)d_in[26];
    const float* dbhh = (const float*)d_in[27];
    const float* rW   = (const float*)d_in[28];
    const float* rb   = (const float*)d_in[29];

    hf_t* wsb  = (hf_t*)d_ws;
    hf_t* scrA = wsb + SCR_A;
    hf_t* scrB = wsb + SCR_B;

    // allow >64KB dynamic LDS (one-time attribute; host-side, graph-safe)
    static bool attr_set = false;
    if (!attr_set) {
        hipFuncSetAttribute((const void*)dsrnn_kernel,
                            hipFuncAttributeMaxDynamicSharedMemorySize, LDS_BYTES);
        attr_set = true;
    }

    convw_kernel<<<512, 256, 0, stream>>>(WeW, Ue2W, eWih, eWhh, mWih, mWhh,
                                          dWih, dWhh, WdW, UdW, wsb);

    dsrnn_kernel<<<B_ / BB, TB, LDS_BYTES, stream>>>(
        inp, UeW, Ueb, Ue2b, Web, VeW, Veb, Udb, Wdb, VdW, Vdb,
        ebih, ebhh, mbih, mbhh, dbih, dbhh, rW, rb,
        wsb, scrA, scrB, (float*)d_out);
}

// Round 8
// 13443.216 us; speedup vs baseline: 1.0673x; 1.0673x over previous
//
#include <hip/hip_runtime.h>

// DA-RNN persistent kernel, round 10: LDS-resident attention operands.
// R4-R7 proved the compiler pins 1024-thread kernels at 64 VGPRs (5x) ->
// register residency is unreachable. But the 8.4 GB uexT re-read stream is
// timestep-INVARIANT block-private data: at BB=2 it is exactly 128 KB and
// the CU has 160 KB LDS (R7 proved >64KB dynamic LDS launches).
//  - BB=2, TB=1024, 160 KB dynamic LDS: u1 region (128 KB) + wk (32 KB,
//    R2's proven working layout).
//  - Phase 0 writes uexT straight to LDS. Encoder scores read LDS only.
//  - After encoder, u1 region is REUSED for udmT (udm pass writes LDS,
//    decoder scores read LDS). scrA eliminated entirely.
//  - udm pass drops R2's m[32] reg-cache (it spilled): mid rows are
//    L1/L2-served re-reads (one-time, cache-hot).
// Math identical to R2 (passed, absmax 9.77e-4).

#define B_   1024
#define T_   128     // T_ENCO
#define NI_  128     // N_INP
#define H_   256     // N_HID
#define H4_  1024    // 4*N_HID
#define TD_  24      // T_DECO
#define DS_  30      // decoder steps
#define BB   2       // batch rows per workgroup
#define TB   1024    // threads per block
#define LDS_BYTES 163840u   // 128 KB u1 (uexT -> udmT) + 32 KB working

typedef _Float16 hf_t;
typedef _Float16 half8  __attribute__((ext_vector_type(8)));
typedef _Float16 half2v __attribute__((ext_vector_type(2)));

__device__ __forceinline__ float sigm(float x) {
    return __builtin_amdgcn_rcpf(1.0f + __expf(-x));
}
__device__ __forceinline__ float tanh_f(float x) {
    float e = __expf(2.0f * x);
    return 1.0f - 2.0f * __builtin_amdgcn_rcpf(e + 1.0f);
}
__device__ __forceinline__ float fdot2f(half2v a, half2v b, float c) {
#if __has_builtin(__builtin_amdgcn_fdot2)
    return __builtin_amdgcn_fdot2(a, b, c, false);
#else
    return fmaf((float)a.x, (float)b.x, fmaf((float)a.y, (float)b.y, c));
#endif
}
__device__ __forceinline__ float dot8h(half8 w, half8 x, float acc) {
    acc = fdot2f(__builtin_shufflevector(w, w, 0, 1), __builtin_shufflevector(x, x, 0, 1), acc);
    acc = fdot2f(__builtin_shufflevector(w, w, 2, 3), __builtin_shufflevector(x, x, 2, 3), acc);
    acc = fdot2f(__builtin_shufflevector(w, w, 4, 5), __builtin_shufflevector(x, x, 4, 5), acc);
    acc = fdot2f(__builtin_shufflevector(w, w, 6, 7), __builtin_shufflevector(x, x, 6, 7), acc);
    return acc;
}

// ---- f16 weight layout inside d_ws (offsets in halves) ----
#define W_WE    0u
#define W_UE2   131072u
#define W_EWIH  163840u
#define W_EWHH  294912u
#define W_MWIH  557056u
#define W_MWHH  819200u
#define W_DWIH  1081344u
#define W_DWHH  1343488u
#define W_WD    1605632u
#define W_UD    1736704u
#define SCR_B   35651584u      // midb [b][t][k]  (unchanged position in ws)

__global__ void convw_kernel(const float* __restrict__ sWE, const float* __restrict__ sUE2,
                             const float* __restrict__ sEI, const float* __restrict__ sEH,
                             const float* __restrict__ sMI, const float* __restrict__ sMH,
                             const float* __restrict__ sDI, const float* __restrict__ sDH,
                             const float* __restrict__ sWD, const float* __restrict__ sUD,
                             hf_t* __restrict__ dst) {
    const int gtid = blockIdx.x * blockDim.x + threadIdx.x;
    const int gs   = gridDim.x * blockDim.x;
    for (int n = gtid; n < 131072; n += gs) {       // WE'
        int e = n & 7, q = n >> 3, k = q & 255, c = q >> 8, kq = c >> 4, i = c & 15;
        dst[W_WE + n] = (hf_t)sWE[k * 512 + kq * 128 + i * 8 + e];
    }
    for (int n = gtid; n < 32768; n += gs) {        // UE2'
        int e = n & 7, q = n >> 3, k = q & 255, c = q >> 8, kq = c >> 2, i = c & 3;
        dst[W_UE2 + n] = (hf_t)sUE2[k * 128 + kq * 32 + i * 8 + e];
    }
    for (int n = gtid; n < 131072; n += gs) {       // EWIH' (K=128)
        int e = n & 7, q = n >> 3, o = q & 1023, i = q >> 10;
        dst[W_EWIH + n] = (hf_t)sEI[o * 128 + i * 8 + e];
    }
    for (int n = gtid; n < 262144; n += gs) {       // K=256 gates
        int e = n & 7, q = n >> 3, o = q & 1023, i = q >> 10;
        int s = o * 256 + i * 8 + e;
        dst[W_EWHH + n] = (hf_t)sEH[s];
        dst[W_MWIH + n] = (hf_t)sMI[s];
        dst[W_MWHH + n] = (hf_t)sMH[s];
        dst[W_DWIH + n] = (hf_t)sDI[s];
        dst[W_DWHH + n] = (hf_t)sDH[s];
    }
    for (int n = gtid; n < 131072; n += gs) {       // WD'
        int e = n & 7, q = n >> 3, k = q & 255, c = q >> 8, kq = c >> 4, i = c & 15;
        dst[W_WD + n] = (hf_t)sWD[k * 512 + kq * 128 + i * 8 + e];
    }
    for (int n = gtid; n < 65536; n += gs)          // UD plain
        dst[W_UD + n] = (hf_t)sUD[n];
}

// ---- working-area offsets (floats, relative to wk = sm + 32768) ----
#define O_HC    0        // hf [2][512]
#define O_CF    512      // f32 [2][256]
#define O_HM    1024     // hf [2][256]
#define O_CMF   1280     // f32 [2][256]
#define O_XRAW  1792     // f32 [2][128]
#define O_XH    2048     // hf [2][128]
#define O_XG    2176     // hf [2][128]
#define O_HCXI  2304     // f32 [2][256]
#define O_SPART 2816     // f32 [1024]
#define O_SBUF  3840     // f32 [2][128]
#define O_GBUF  4096     // f32 [2048]
#define O_DINH  6144     // hf [2][256]
#define O_HF    6400     // f32 [2][256]
#define O_VES   6912     // f32 [256]
#define O_VDS   7168     // f32 [256]
// phase-0 X staging reuses wk[0..8192) as f32[128][64]

__global__ __launch_bounds__(TB, 4) void dsrnn_kernel(
    const float* __restrict__ inp,
    const float* __restrict__ UeW,  const float* __restrict__ Ueb,
    const float* __restrict__ Ue2b,
    const float* __restrict__ Web,
    const float* __restrict__ VeW,  const float* __restrict__ Veb,
    const float* __restrict__ Udb,
    const float* __restrict__ Wdb,
    const float* __restrict__ VdW,  const float* __restrict__ Vdb,
    const float* __restrict__ ebih, const float* __restrict__ ebhh,
    const float* __restrict__ mbih, const float* __restrict__ mbhh,
    const float* __restrict__ dbih, const float* __restrict__ dbhh,
    const float* __restrict__ rW,   const float* __restrict__ rb,
    const hf_t* __restrict__ wb,
    hf_t* __restrict__ scrB,
    float* __restrict__ out)
{
    extern __shared__ float sm[];
    hf_t*  u1 = (hf_t*)sm;          // 131072 B: uexT[b][k][j], later udmT[b][o][t]
    float* wk = sm + 32768;         // 8192 floats working area

    const int tid = threadIdx.x;
    const int b0  = blockIdx.x * BB;

    hf_t*  hc   = (hf_t*)(wk + O_HC);
    float* cf   = wk + O_CF;
    hf_t*  hm   = (hf_t*)(wk + O_HM);
    float* cmf  = wk + O_CMF;
    float* xraw = wk + O_XRAW;
    hf_t*  xh   = (hf_t*)(wk + O_XH);
    hf_t*  xg   = (hf_t*)(wk + O_XG);
    float* hcxi = wk + O_HCXI;
    float* spart= wk + O_SPART;
    float* sbuf = wk + O_SBUF;
    float* gbuf = wk + O_GBUF;
    hf_t*  dinh = (hf_t*)(wk + O_DINH);
    float* hful = wk + O_HF;
    float* ves  = wk + O_VES;
    float* vds  = wk + O_VDS;

    // ---------- Phase 0: uexT[b][k][j] -> LDS u1, exact f32 accumulate ----------
    {
        const int jj = tid & 63;        // j within half
        const int kg = tid >> 6;        // 16 groups x 16 k
        for (int b = 0; b < BB; ++b) {
            const float* Xg = inp + (size_t)(b0 + b) * T_ * NI_;
            for (int jh = 0; jh < 2; ++jh) {
                __syncthreads();
                for (int i = tid; i < 128 * 64; i += TB) {
                    int t = i >> 6, j2 = i & 63;
                    wk[i] = Xg[t * NI_ + jh * 64 + j2];
                }
                __syncthreads();
                const int j = jh * 64 + jj;
                for (int k = kg * 16; k < kg * 16 + 16; ++k) {
                    const float* wrow = UeW + (size_t)k * T_;
                    float acc = Ueb[k];
#pragma unroll 4
                    for (int t = 0; t < T_; ++t) acc = fmaf(wrow[t], wk[t * 64 + jj], acc);
                    u1[((size_t)(b * 256) + k) * 128 + j] = (hf_t)acc;
                }
            }
        }
    }
    __syncthreads();
    for (int i = tid; i < 2048; i += TB) wk[i] = 0.0f;   // zero h/c enc+mid
    if (tid < 256) { ves[tid] = VeW[tid]; vds[tid] = VdW[tid]; }
    __syncthreads();

    // ---------- Fused encoder + mid loop ----------
    for (int t = 0; t < T_; ++t) {
        // (a) load x_t
        if (tid < 256) {
            const int b = tid >> 7, j = tid & 127;
            float v = inp[((size_t)(b0 + b) * T_ + t) * NI_ + j];
            xraw[b * NI_ + j] = v;
            xh[b * NI_ + j]   = (hf_t)v;
        }
        __syncthreads();

        // (b) We.[h;c] + Ue2.x partials, k-quarter split, 2 batches
        {
            const int k = tid & 255, kq = tid >> 8;
            const half8* wWE = (const half8*)(wb + W_WE)  + (size_t)(kq * 16) * 256 + k;
            const half8* wU2 = (const half8*)(wb + W_UE2) + (size_t)(kq * 4)  * 256 + k;
            float a0 = 0.f, a1 = 0.f;
#pragma unroll 8
            for (int i = 0; i < 16; ++i) {
                half8 w = wWE[(size_t)i * 256];
                a0 = dot8h(w, *(const half8*)&hc[0 * 512 + kq * 128 + i * 8], a0);
                a1 = dot8h(w, *(const half8*)&hc[1 * 512 + kq * 128 + i * 8], a1);
            }
#pragma unroll
            for (int i = 0; i < 4; ++i) {
                half8 w = wU2[(size_t)i * 256];
                a0 = dot8h(w, *(const half8*)&xh[0 * 128 + kq * 32 + i * 8], a0);
                a1 = dot8h(w, *(const half8*)&xh[1 * 128 + kq * 32 + i * 8], a1);
            }
            gbuf[kq * 512 + 0 * 256 + k] = a0;
            gbuf[kq * 512 + 1 * 256 + k] = a1;
        }
        __syncthreads();
        if (tid < 512) {
            const int b = tid >> 8, k = tid & 255;
            hcxi[b * 256 + k] = gbuf[b * 256 + k] + gbuf[512 + b * 256 + k]
                              + gbuf[1024 + b * 256 + k] + gbuf[1536 + b * 256 + k]
                              + Web[k] + Ue2b[k];
        }
        __syncthreads();

        // (c) scores from LDS-resident uexT: b(2) x kq(4) x j(128), 64 k each
        {
            const int b = tid >> 9, kq = (tid >> 7) & 3, j = tid & 127;
            const hf_t* up = u1 + ((size_t)(b * 256 + kq * 64)) * 128 + j;
            const float* hx = hcxi + b * 256 + kq * 64;
            const float* vw = ves + kq * 64;
            float acc = (kq == 0) ? Veb[0] : 0.f;
#pragma unroll 8
            for (int k2 = 0; k2 < 64; ++k2) {
                float u = (float)up[(size_t)k2 * 128];
                acc = fmaf(vw[k2], tanh_f(hx[k2] + u), acc);
            }
            spart[tid] = acc;
        }
        __syncthreads();

        // (d) softmax per b (one wave per b), gate x
        if (tid < 128) {
            const int b = tid >> 6, lane = tid & 63;
            const int base = b << 9;
            float sA = spart[base + lane]       + spart[base + 128 + lane]
                     + spart[base + 256 + lane] + spart[base + 384 + lane];
            float sB = spart[base + 64 + lane]  + spart[base + 192 + lane]
                     + spart[base + 320 + lane] + spart[base + 448 + lane];
            float m = fmaxf(sA, sB);
            for (int d = 1; d < 64; d <<= 1) m = fmaxf(m, __shfl_xor(m, d));
            float eA = __expf(sA - m), eB = __expf(sB - m);
            float ssum = eA + eB;
            for (int d = 1; d < 64; d <<= 1) ssum += __shfl_xor(ssum, d);
            float inv = 1.0f / ssum;
            xg[b * NI_ + lane]      = (hf_t)(xraw[b * NI_ + lane] * eA * inv);
            xg[b * NI_ + lane + 64] = (hf_t)(xraw[b * NI_ + lane + 64] * eB * inv);
        }
        __syncthreads();

        // (e) encoder gates: thread o owns row o (read exactly once)
        {
            const int o = tid;
            const half8* wih = (const half8*)(wb + W_EWIH) + o;
            const half8* whh = (const half8*)(wb + W_EWHH) + o;
            float bias = ebih[o] + ebhh[o];
            float a0 = bias, a1 = bias;
#pragma unroll 8
            for (int i = 0; i < 16; ++i) {
                half8 w = wih[(size_t)i * 1024];
                a0 = dot8h(w, *(const half8*)&xg[0 * 128 + i * 8], a0);
                a1 = dot8h(w, *(const half8*)&xg[1 * 128 + i * 8], a1);
            }
#pragma unroll 8
            for (int i = 0; i < 32; ++i) {
                half8 w = whh[(size_t)i * 1024];
                a0 = dot8h(w, *(const half8*)&hc[0 * 512 + i * 8], a0);
                a1 = dot8h(w, *(const half8*)&hc[1 * 512 + i * 8], a1);
            }
            gbuf[0 * 1024 + o] = a0; gbuf[1 * 1024 + o] = a1;
        }
        __syncthreads();

        // (f) encoder LSTM update
        if (tid < 512) {
            const int b = tid >> 8, k = tid & 255;
            float gi = gbuf[b * H4_ + k];
            float gf = gbuf[b * H4_ + H_ + k];
            float gg = gbuf[b * H4_ + 2 * H_ + k];
            float go = gbuf[b * H4_ + 3 * H_ + k];
            float c2 = sigm(gf) * cf[b * H_ + k] + sigm(gi) * tanh_f(gg);
            float h2 = sigm(go) * tanh_f(c2);
            cf[b * H_ + k] = c2;
            hc[b * 512 + k]       = (hf_t)h2;
            hc[b * 512 + 256 + k] = (hf_t)c2;
        }
        __syncthreads();

        // (g) mid gates
        {
            const int o = tid;
            const half8* wih = (const half8*)(wb + W_MWIH) + o;
            const half8* whh = (const half8*)(wb + W_MWHH) + o;
            float bias = mbih[o] + mbhh[o];
            float a0 = bias, a1 = bias;
#pragma unroll 8
            for (int i = 0; i < 32; ++i) {
                half8 w = wih[(size_t)i * 1024];
                a0 = dot8h(w, *(const half8*)&hc[0 * 512 + i * 8], a0);
                a1 = dot8h(w, *(const half8*)&hc[1 * 512 + i * 8], a1);
            }
#pragma unroll 8
            for (int i = 0; i < 32; ++i) {
                half8 w = whh[(size_t)i * 1024];
                a0 = dot8h(w, *(const half8*)&hm[0 * 256 + i * 8], a0);
                a1 = dot8h(w, *(const half8*)&hm[1 * 256 + i * 8], a1);
            }
            gbuf[0 * 1024 + o] = a0; gbuf[1 * 1024 + o] = a1;
        }
        __syncthreads();

        // (h) mid LSTM update + store mid
        if (tid < 512) {
            const int b = tid >> 8, k = tid & 255;
            float gi = gbuf[b * H4_ + k];
            float gf = gbuf[b * H4_ + H_ + k];
            float gg = gbuf[b * H4_ + 2 * H_ + k];
            float go = gbuf[b * H4_ + 3 * H_ + k];
            float c2 = sigm(gf) * cmf[b * H_ + k] + sigm(gi) * tanh_f(gg);
            float h2 = sigm(go) * tanh_f(c2);
            cmf[b * H_ + k] = c2;
            hm[b * 256 + k] = (hf_t)h2;
            scrB[((size_t)(b0 + b) * T_ + t) * H_ + k] = (hf_t)h2;
        }
        __syncthreads();
    }

    // ---------- udm pass: u1[b][o][tt] = UdW[o,:].mid[b,tt,:] + Udb[o] ----------
    // mid rows served by L1/L2 (no reg cache -> no spill); writes to LDS.
    {
        const int b = tid >> 9, r = tid & 511, oq = r >> 7, tt = r & 127;
        const half8* mrow = (const half8*)(scrB + ((size_t)(b0 + b) * T_ + tt) * H_);
        const half8* udw = (const half8*)(wb + W_UD);
        for (int o2 = 0; o2 < 64; ++o2) {
            const int o = oq * 64 + o2;
            const half8* ur = udw + (size_t)o * 32;
            float acc = Udb[o];
#pragma unroll 8
            for (int i = 0; i < 32; ++i) acc = dot8h(ur[i], mrow[i], acc);
            u1[((size_t)(b * 256) + o) * 128 + tt] = (hf_t)acc;
        }
    }
    __syncthreads();
    for (int i = tid; i < 1024; i += TB) wk[i] = 0.0f;   // zero dec h/c
    __syncthreads();

    // ---------- Decoder ----------
    for (int s = 0; s < DS_; ++s) {
        // (a') Wd.[h;c] partials, k-quarter split, 2 batches
        {
            const int k = tid & 255, kq = tid >> 8;
            const half8* wWD = (const half8*)(wb + W_WD) + (size_t)(kq * 16) * 256 + k;
            float a0 = 0.f, a1 = 0.f;
#pragma unroll 8
            for (int i = 0; i < 16; ++i) {
                half8 w = wWD[(size_t)i * 256];
                a0 = dot8h(w, *(const half8*)&hc[0 * 512 + kq * 128 + i * 8], a0);
                a1 = dot8h(w, *(const half8*)&hc[1 * 512 + kq * 128 + i * 8], a1);
            }
            gbuf[kq * 512 + 0 * 256 + k] = a0;
            gbuf[kq * 512 + 1 * 256 + k] = a1;
        }
        __syncthreads();
        if (tid < 512) {
            const int b = tid >> 8, k = tid & 255;
            hcxi[b * 256 + k] = gbuf[b * 256 + k] + gbuf[512 + b * 256 + k]
                              + gbuf[1024 + b * 256 + k] + gbuf[1536 + b * 256 + k]
                              + Wdb[k];
        }
        __syncthreads();

        // (b') temporal scores from LDS-resident udmT
        {
            const int b = tid >> 9, kq = (tid >> 7) & 3, j = tid & 127;
            const hf_t* up = u1 + ((size_t)(b * 256 + kq * 64)) * 128 + j;
            const float* hx = hcxi + b * 256 + kq * 64;
            const float* vw = vds + kq * 64;
            float acc = (kq == 0) ? Vdb[0] : 0.f;
#pragma unroll 8
            for (int k2 = 0; k2 < 64; ++k2) {
                float u = (float)up[(size_t)k2 * 128];
                acc = fmaf(vw[k2], tanh_f(hx[k2] + u), acc);
            }
            spart[tid] = acc;
        }
        __syncthreads();
        if (tid < 256) {
            const int b = tid >> 7, j = tid & 127;
            const int base = b << 9;
            sbuf[b * T_ + j] = spart[base + j] + spart[base + 128 + j]
                             + spart[base + 256 + j] + spart[base + 384 + j];
        }
        __syncthreads();

        // (d') dec_in[b,h] = sum_j t[b,j] * mid[b,j,h]; split j into 2 halves
        {
            const int b = tid >> 9, jh = (tid >> 8) & 1, h = tid & 255;
            const hf_t* mp = scrB + (size_t)(b0 + b) * T_ * H_ + h;
            float acc = 0.0f;
            const int jbase = jh * 64;
            for (int j = 0; j < 64; ++j)
                acc = fmaf(sbuf[b * T_ + jbase + j], (float)mp[(size_t)(jbase + j) * H_], acc);
            gbuf[(b * 2 + jh) * 256 + h] = acc;
        }
        __syncthreads();
        if (tid < 512) {
            const int b = tid >> 8, h = tid & 255;
            dinh[b * 256 + h] = (hf_t)(gbuf[b * 512 + h] + gbuf[b * 512 + 256 + h]);
        }
        __syncthreads();

        // (e') decoder gates
        {
            const int o = tid;
            const half8* wih = (const half8*)(wb + W_DWIH) + o;
            const half8* whh = (const half8*)(wb + W_DWHH) + o;
            float bias = dbih[o] + dbhh[o];
            float a0 = bias, a1 = bias;
#pragma unroll 8
            for (int i = 0; i < 32; ++i) {
                half8 w = wih[(size_t)i * 1024];
                a0 = dot8h(w, *(const half8*)&dinh[0 * 256 + i * 8], a0);
                a1 = dot8h(w, *(const half8*)&dinh[1 * 256 + i * 8], a1);
            }
#pragma unroll 8
            for (int i = 0; i < 32; ++i) {
                half8 w = whh[(size_t)i * 1024];
                a0 = dot8h(w, *(const half8*)&hc[0 * 512 + i * 8], a0);
                a1 = dot8h(w, *(const half8*)&hc[1 * 512 + i * 8], a1);
            }
            gbuf[0 * 1024 + o] = a0; gbuf[1 * 1024 + o] = a1;
        }
        __syncthreads();

        // (f') decoder LSTM update
        if (tid < 512) {
            const int b = tid >> 8, k = tid & 255;
            float gi = gbuf[b * H4_ + k];
            float gf = gbuf[b * H4_ + H_ + k];
            float gg = gbuf[b * H4_ + 2 * H_ + k];
            float go = gbuf[b * H4_ + 3 * H_ + k];
            float c2 = sigm(gf) * cf[b * H_ + k] + sigm(gi) * tanh_f(gg);
            float h2 = sigm(go) * tanh_f(c2);
            cf[b * H_ + k] = c2;
            hc[b * 512 + k]       = (hf_t)h2;
            hc[b * 512 + 256 + k] = (hf_t)c2;
            hful[b * H_ + k] = h2;
        }
        __syncthreads();

        // (g') out[b, s-6] = rW.h + rb
        if (s >= 6 && tid < 128) {
            const int b = tid >> 6, lane = tid & 63;
            float p = rW[lane]       * hful[b * H_ + lane]
                    + rW[lane + 64]  * hful[b * H_ + lane + 64]
                    + rW[lane + 128] * hful[b * H_ + lane + 128]
                    + rW[lane + 192] * hful[b * H_ + lane + 192];
            for (int d = 1; d < 64; d <<= 1) p += __shfl_xor(p, d);
            if (lane == 0) out[(size_t)(b0 + b) * TD_ + (s - 6)] = p + rb[0];
        }
        __syncthreads();
    }
}

extern "C" void kernel_launch(void* const* d_in, const int* in_sizes, int n_in,
                              void* d_out, int out_size, void* d_ws, size_t ws_size,
                              hipStream_t stream) {
    const float* inp  = (const float*)d_in[0];
    const float* UeW  = (const float*)d_in[2];
    const float* Ueb  = (const float*)d_in[3];
    const float* Ue2W = (const float*)d_in[4];
    const float* Ue2b = (const float*)d_in[5];
    const float* WeW  = (const float*)d_in[6];
    const float* Web  = (const float*)d_in[7];
    const float* VeW  = (const float*)d_in[8];
    const float* Veb  = (const float*)d_in[9];
    const float* UdW  = (const float*)d_in[10];
    const float* Udb  = (const float*)d_in[11];
    const float* WdW  = (const float*)d_in[12];
    const float* Wdb  = (const float*)d_in[13];
    const float* VdW  = (const float*)d_in[14];
    const float* Vdb  = (const float*)d_in[15];
    const float* eWih = (const float*)d_in[16];
    const float* eWhh = (const float*)d_in[17];
    const float* ebih = (const float*)d_in[18];
    const float* ebhh = (const float*)d_in[19];
    const float* mWih = (const float*)d_in[20];
    const float* mWhh = (const float*)d_in[21];
    const float* mbih = (const float*)d_in[22];
    const float* mbhh = (const float*)d_in[23];
    const float* dWih = (const float*)d_in[24];
    const float* dWhh = (const float*)d_in[25];
    const float* dbih = (const float*)d_in[26];
    const float* dbhh = (const float*)d_in[27];
    const float* rW   = (const float*)d_in[28];
    const float* rb   = (const float*)d_in[29];

    hf_t* wsb  = (hf_t*)d_ws;
    hf_t* scrB = wsb + SCR_B;

    // allow 160 KB dynamic LDS (one-time attribute; host-side, graph-safe)
    static bool attr_set = false;
    if (!attr_set) {
        hipFuncSetAttribute((const void*)dsrnn_kernel,
                            hipFuncAttributeMaxDynamicSharedMemorySize, LDS_BYTES);
        attr_set = true;
    }

    convw_kernel<<<512, 256, 0, stream>>>(WeW, Ue2W, eWih, eWhh, mWih, mWhh,
                                          dWih, dWhh, WdW, UdW, wsb);

    dsrnn_kernel<<<B_ / BB, TB, LDS_BYTES, stream>>>(
        inp, UeW, Ueb, Ue2b, Web, VeW, Veb, Udb, Wdb, VdW, Vdb,
        ebih, ebhh, mbih, mbhh, dbih, dbhh, rW, rb,
        wsb, scrB, (float*)d_out);
}

// Round 9
// 10307.674 us; speedup vs baseline: 1.3919x; 1.3042x over previous
//
#include <hip/hip_runtime.h>

// DA-RNN persistent kernel, round 11: BB=4 + HALF-resident attention operands.
// R8 post-mortem: full-LDS at BB=2 cut FETCH 5x but serialized (512 blocks,
// 1/CU -> 2 passes) and doubled the L2 weight stream -> 13.4 ms. This round
// keeps BB=4 (grid 256, 1 block/CU, best weight amortization) and stores the
// k<128 HALF of uexT (128 KB f16) in LDS; k>=128 streams from HBM as in R0.
// The decoder reuses the same 128 KB for the o<128 half of udmT.
// To fit wk in 32 KB: c-states (enc/mid/dec, f32) live in REGISTERS (the
// (f)/(h)/(f') threads keep the same (b,k)=tid mapping every step), xh/xg
// share one buffer, spart folds into gbuf, and the output projection uses a
// wave-shuffle reduce (hful eliminated). Math identical to R0 (f16 operands,
// f32 states); only the tiny output-dot summation order changes.
// LDS: wk 32 KB [0..8192 f) + u1 128 KB = 160 KB exactly (R8 proved dynamic).

#define B_   1024
#define T_   128     // T_ENCO
#define NI_  128     // N_INP
#define H_   256     // N_HID
#define H4_  1024    // 4*N_HID
#define TD_  24      // T_DECO
#define DS_  30      // decoder steps
#define BB   4       // batch rows per workgroup
#define TB   1024    // threads per block
#define LDS_BYTES 163840u   // 32 KB wk + 128 KB u1

typedef _Float16 hf_t;
typedef _Float16 half8  __attribute__((ext_vector_type(8)));
typedef _Float16 half2v __attribute__((ext_vector_type(2)));

__device__ __forceinline__ float sigm(float x) {
    return __builtin_amdgcn_rcpf(1.0f + __expf(-x));
}
__device__ __forceinline__ float tanh_f(float x) {
    float e = __expf(2.0f * x);
    return 1.0f - 2.0f * __builtin_amdgcn_rcpf(e + 1.0f);
}
__device__ __forceinline__ float fdot2f(half2v a, half2v b, float c) {
#if __has_builtin(__builtin_amdgcn_fdot2)
    return __builtin_amdgcn_fdot2(a, b, c, false);
#else
    return fmaf((float)a.x, (float)b.x, fmaf((float)a.y, (float)b.y, c));
#endif
}
__device__ __forceinline__ float dot8h(half8 w, half8 x, float acc) {
    acc = fdot2f(__builtin_shufflevector(w, w, 0, 1), __builtin_shufflevector(x, x, 0, 1), acc);
    acc = fdot2f(__builtin_shufflevector(w, w, 2, 3), __builtin_shufflevector(x, x, 2, 3), acc);
    acc = fdot2f(__builtin_shufflevector(w, w, 4, 5), __builtin_shufflevector(x, x, 4, 5), acc);
    acc = fdot2f(__builtin_shufflevector(w, w, 6, 7), __builtin_shufflevector(x, x, 6, 7), acc);
    return acc;
}
__device__ __forceinline__ hf_t nt_load_h(const hf_t* p) {
#if __has_builtin(__builtin_nontemporal_load)
    return __builtin_nontemporal_load(p);
#else
    return *p;
#endif
}
__device__ __forceinline__ void nt_store_h(hf_t v, hf_t* p) {
#if __has_builtin(__builtin_nontemporal_store)
    __builtin_nontemporal_store(v, p);
#else
    *p = v;
#endif
}

// ---- f16 weight layout inside d_ws (offsets in halves) ----
#define W_WE    0u
#define W_UE2   131072u
#define W_EWIH  163840u
#define W_EWHH  294912u
#define W_MWIH  557056u
#define W_MWHH  819200u
#define W_DWIH  1081344u
#define W_DWHH  1343488u
#define W_WD    1605632u
#define W_UD    1736704u
#define SCR_A   2097152u       // upper halves: uexT k>=128 -> udmT o>=128 [b][127..0][j]
#define SCR_B   35651584u      // midb [b][t][k]

__global__ void convw_kernel(const float* __restrict__ sWE, const float* __restrict__ sUE2,
                             const float* __restrict__ sEI, const float* __restrict__ sEH,
                             const float* __restrict__ sMI, const float* __restrict__ sMH,
                             const float* __restrict__ sDI, const float* __restrict__ sDH,
                             const float* __restrict__ sWD, const float* __restrict__ sUD,
                             hf_t* __restrict__ dst) {
    const int gtid = blockIdx.x * blockDim.x + threadIdx.x;
    const int gs   = gridDim.x * blockDim.x;
    for (int n = gtid; n < 131072; n += gs) {       // WE'
        int e = n & 7, q = n >> 3, k = q & 255, c = q >> 8, kq = c >> 4, i = c & 15;
        dst[W_WE + n] = (hf_t)sWE[k * 512 + kq * 128 + i * 8 + e];
    }
    for (int n = gtid; n < 32768; n += gs) {        // UE2'
        int e = n & 7, q = n >> 3, k = q & 255, c = q >> 8, kq = c >> 2, i = c & 3;
        dst[W_UE2 + n] = (hf_t)sUE2[k * 128 + kq * 32 + i * 8 + e];
    }
    for (int n = gtid; n < 131072; n += gs) {       // EWIH' (K=128)
        int e = n & 7, q = n >> 3, o = q & 1023, i = q >> 10;
        dst[W_EWIH + n] = (hf_t)sEI[o * 128 + i * 8 + e];
    }
    for (int n = gtid; n < 262144; n += gs) {       // K=256 gates
        int e = n & 7, q = n >> 3, o = q & 1023, i = q >> 10;
        int s = o * 256 + i * 8 + e;
        dst[W_EWHH + n] = (hf_t)sEH[s];
        dst[W_MWIH + n] = (hf_t)sMI[s];
        dst[W_MWHH + n] = (hf_t)sMH[s];
        dst[W_DWIH + n] = (hf_t)sDI[s];
        dst[W_DWHH + n] = (hf_t)sDH[s];
    }
    for (int n = gtid; n < 131072; n += gs) {       // WD'
        int e = n & 7, q = n >> 3, k = q & 255, c = q >> 8, kq = c >> 4, i = c & 15;
        dst[W_WD + n] = (hf_t)sWD[k * 512 + kq * 128 + i * 8 + e];
    }
    for (int n = gtid; n < 65536; n += gs)          // UD plain
        dst[W_UD + n] = (hf_t)sUD[n];
}

// ---- wk offsets (floats, wk = sm[0..8192)) ----
#define O_HC    0        // hf [4][512]                      1024f
#define O_HM    1024     // hf [4][256] (decoder: dinh)       512f
#define O_XRAW  1536     // f32 [4][128]                      512f
#define O_XHG   2048     // hf [4][128]  xh then xg           256f
#define O_HCXI  2304     // f32 [4][256]                     1024f
#define O_VES   3328     // f32 [256]
#define O_VDS   3584     // f32 [256]
#define O_RED   3840     // f32 [16] output-reduce partials
#define O_GBUF  4096     // f32 [4096] gates / partials / scores / sbuf
// phase-0 X staging reuses wk[0..8192) as f32[128][64]

__global__ __launch_bounds__(TB, 4) void dsrnn_kernel(
    const float* __restrict__ inp,
    const float* __restrict__ UeW,  const float* __restrict__ Ueb,
    const float* __restrict__ Ue2b,
    const float* __restrict__ Web,
    const float* __restrict__ VeW,  const float* __restrict__ Veb,
    const float* __restrict__ Udb,
    const float* __restrict__ Wdb,
    const float* __restrict__ VdW,  const float* __restrict__ Vdb,
    const float* __restrict__ ebih, const float* __restrict__ ebhh,
    const float* __restrict__ mbih, const float* __restrict__ mbhh,
    const float* __restrict__ dbih, const float* __restrict__ dbhh,
    const float* __restrict__ rW,   const float* __restrict__ rb,
    const hf_t* __restrict__ wb,
    hf_t* __restrict__ scrA,
    hf_t* __restrict__ scrB,
    float* __restrict__ out)
{
    extern __shared__ float sm[];
    float* wk = sm;                       // 8192 floats = 32 KB
    hf_t*  u1 = (hf_t*)(sm + 8192);       // 65536 halves = 128 KB

    const int tid = threadIdx.x;
    const int b0  = blockIdx.x * BB;

    hf_t*  hc   = (hf_t*)(wk + O_HC);
    hf_t*  hm   = (hf_t*)(wk + O_HM);
    float* xraw = wk + O_XRAW;
    hf_t*  xhg  = (hf_t*)(wk + O_XHG);
    float* hcxi = wk + O_HCXI;
    float* ves  = wk + O_VES;
    float* vds  = wk + O_VDS;
    float* red  = wk + O_RED;
    float* gbuf = wk + O_GBUF;
    hf_t*  dinh = (hf_t*)(wk + O_HM);     // decoder alias of HM

    // ---------- Phase 0: uexT; k<128 -> LDS u1, k>=128 -> scrA (nt) ----------
    {
        const int jj = tid & 63;        // j within half
        const int kg = tid >> 6;        // 16 groups x 16 k
        for (int b = 0; b < BB; ++b) {
            const float* Xg = inp + (size_t)(b0 + b) * T_ * NI_;
            for (int jh = 0; jh < 2; ++jh) {
                __syncthreads();
                for (int i = tid; i < 128 * 64; i += TB) {
                    int t = i >> 6, j2 = i & 63;
                    wk[i] = Xg[t * NI_ + jh * 64 + j2];
                }
                __syncthreads();
                const int j = jh * 64 + jj;
                for (int k = kg * 16; k < kg * 16 + 16; ++k) {
                    const float* wrow = UeW + (size_t)k * T_;
                    float acc = Ueb[k];
#pragma unroll 4
                    for (int t = 0; t < T_; ++t) acc = fmaf(wrow[t], wk[t * 64 + jj], acc);
                    if (k < 128)
                        u1[((size_t)(b * 128) + k) * 128 + j] = (hf_t)acc;
                    else
                        nt_store_h((hf_t)acc,
                                   scrA + (((size_t)(b0 + b) * 128) + (k - 128)) * 128 + j);
                }
            }
        }
    }
    __syncthreads();
    for (int i = tid; i < 1536; i += TB) wk[i] = 0.0f;   // zero hc + hm
    if (tid < 256) { ves[tid] = VeW[tid]; vds[tid] = VdW[tid]; }
    __syncthreads();

    float c_enc = 0.0f, c_mid = 0.0f;   // f32 c-states in registers, (b,k)=tid

    // ---------- Fused encoder + mid loop ----------
    for (int t = 0; t < T_; ++t) {
        // (a) load x_t
        if (tid < 512) {
            const int b = tid >> 7, j = tid & 127;
            float v = inp[((size_t)(b0 + b) * T_ + t) * NI_ + j];
            xraw[b * NI_ + j] = v;
            xhg[b * NI_ + j]  = (hf_t)v;
        }
        __syncthreads();

        // (b) We.[h;c] + Ue2.x partials, k-quarter split
        {
            const int k = tid & 255, kq = tid >> 8;
            const half8* wWE = (const half8*)(wb + W_WE)  + (size_t)(kq * 16) * 256 + k;
            const half8* wU2 = (const half8*)(wb + W_UE2) + (size_t)(kq * 4)  * 256 + k;
            float a0 = 0.f, a1 = 0.f, a2 = 0.f, a3 = 0.f;
#pragma unroll 8
            for (int i = 0; i < 16; ++i) {
                half8 w = wWE[(size_t)i * 256];
                a0 = dot8h(w, *(const half8*)&hc[0 * 512 + kq * 128 + i * 8], a0);
                a1 = dot8h(w, *(const half8*)&hc[1 * 512 + kq * 128 + i * 8], a1);
                a2 = dot8h(w, *(const half8*)&hc[2 * 512 + kq * 128 + i * 8], a2);
                a3 = dot8h(w, *(const half8*)&hc[3 * 512 + kq * 128 + i * 8], a3);
            }
#pragma unroll
            for (int i = 0; i < 4; ++i) {
                half8 w = wU2[(size_t)i * 256];
                a0 = dot8h(w, *(const half8*)&xhg[0 * 128 + kq * 32 + i * 8], a0);
                a1 = dot8h(w, *(const half8*)&xhg[1 * 128 + kq * 32 + i * 8], a1);
                a2 = dot8h(w, *(const half8*)&xhg[2 * 128 + kq * 32 + i * 8], a2);
                a3 = dot8h(w, *(const half8*)&xhg[3 * 128 + kq * 32 + i * 8], a3);
            }
            gbuf[kq * 1024 + 0 * 256 + k] = a0;
            gbuf[kq * 1024 + 1 * 256 + k] = a1;
            gbuf[kq * 1024 + 2 * 256 + k] = a2;
            gbuf[kq * 1024 + 3 * 256 + k] = a3;
        }
        __syncthreads();
        {
            const int b = tid >> 8, k = tid & 255;
            hcxi[b * 256 + k] = gbuf[b * 256 + k] + gbuf[1024 + b * 256 + k]
                              + gbuf[2048 + b * 256 + k] + gbuf[3072 + b * 256 + k]
                              + Web[k] + Ue2b[k];
        }
        __syncthreads();

        // (c) scores: kh=0 from LDS u1, kh=1 from HBM scrA (nt)
        {
            const int b = tid >> 8, r = tid & 255, kh = r >> 7, j = r & 127;
            const float* hx = hcxi + b * 256 + kh * 128;
            const float* vw = ves + kh * 128;
            float acc = kh ? 0.f : Veb[0];
            if (kh == 0) {
                const hf_t* up = u1 + ((size_t)(b * 128)) * 128 + j;
#pragma unroll 8
                for (int k2 = 0; k2 < 128; ++k2) {
                    float u = (float)up[(size_t)k2 * 128];
                    acc = fmaf(vw[k2], tanh_f(hx[k2] + u), acc);
                }
            } else {
                const hf_t* up = scrA + ((size_t)(b0 + b) * 128) * 128 + j;
#pragma unroll 8
                for (int k2 = 0; k2 < 128; ++k2) {
                    float u = (float)nt_load_h(up + (size_t)k2 * 128);
                    acc = fmaf(vw[k2], tanh_f(hx[k2] + u), acc);
                }
            }
            gbuf[tid] = acc;   // score partials in gbuf[0..1024)
        }
        __syncthreads();

        // (d) softmax per b (one wave per b), gate x
        if (tid < 256) {
            const int b = tid >> 6, lane = tid & 63;
            const int base = b << 8;
            float sA = gbuf[base + lane]      + gbuf[base + 128 + lane];
            float sB = gbuf[base + 64 + lane] + gbuf[base + 192 + lane];
            float m = fmaxf(sA, sB);
            for (int d = 1; d < 64; d <<= 1) m = fmaxf(m, __shfl_xor(m, d));
            float eA = __expf(sA - m), eB = __expf(sB - m);
            float ssum = eA + eB;
            for (int d = 1; d < 64; d <<= 1) ssum += __shfl_xor(ssum, d);
            float inv = 1.0f / ssum;
            xhg[b * NI_ + lane]      = (hf_t)(xraw[b * NI_ + lane] * eA * inv);
            xhg[b * NI_ + lane + 64] = (hf_t)(xraw[b * NI_ + lane + 64] * eB * inv);
        }
        __syncthreads();

        // (e) encoder gates: thread o owns row o (read exactly once)
        {
            const int o = tid;
            const half8* wih = (const half8*)(wb + W_EWIH) + o;
            const half8* whh = (const half8*)(wb + W_EWHH) + o;
            float bias = ebih[o] + ebhh[o];
            float a0 = bias, a1 = bias, a2 = bias, a3 = bias;
#pragma unroll 8
            for (int i = 0; i < 16; ++i) {
                half8 w = wih[(size_t)i * 1024];
                a0 = dot8h(w, *(const half8*)&xhg[0 * 128 + i * 8], a0);
                a1 = dot8h(w, *(const half8*)&xhg[1 * 128 + i * 8], a1);
                a2 = dot8h(w, *(const half8*)&xhg[2 * 128 + i * 8], a2);
                a3 = dot8h(w, *(const half8*)&xhg[3 * 128 + i * 8], a3);
            }
#pragma unroll 8
            for (int i = 0; i < 32; ++i) {
                half8 w = whh[(size_t)i * 1024];
                a0 = dot8h(w, *(const half8*)&hc[0 * 512 + i * 8], a0);
                a1 = dot8h(w, *(const half8*)&hc[1 * 512 + i * 8], a1);
                a2 = dot8h(w, *(const half8*)&hc[2 * 512 + i * 8], a2);
                a3 = dot8h(w, *(const half8*)&hc[3 * 512 + i * 8], a3);
            }
            gbuf[0 * 1024 + o] = a0; gbuf[1 * 1024 + o] = a1;
            gbuf[2 * 1024 + o] = a2; gbuf[3 * 1024 + o] = a3;
        }
        __syncthreads();

        // (f) encoder LSTM update (c in register)
        {
            const int b = tid >> 8, k = tid & 255;
            float gi = gbuf[b * H4_ + k];
            float gf = gbuf[b * H4_ + H_ + k];
            float gg = gbuf[b * H4_ + 2 * H_ + k];
            float go = gbuf[b * H4_ + 3 * H_ + k];
            float c2 = sigm(gf) * c_enc + sigm(gi) * tanh_f(gg);
            float h2 = sigm(go) * tanh_f(c2);
            c_enc = c2;
            hc[b * 512 + k]       = (hf_t)h2;
            hc[b * 512 + 256 + k] = (hf_t)c2;
        }
        __syncthreads();

        // (g) mid gates
        {
            const int o = tid;
            const half8* wih = (const half8*)(wb + W_MWIH) + o;
            const half8* whh = (const half8*)(wb + W_MWHH) + o;
            float bias = mbih[o] + mbhh[o];
            float a0 = bias, a1 = bias, a2 = bias, a3 = bias;
#pragma unroll 8
            for (int i = 0; i < 32; ++i) {
                half8 w = wih[(size_t)i * 1024];
                a0 = dot8h(w, *(const half8*)&hc[0 * 512 + i * 8], a0);
                a1 = dot8h(w, *(const half8*)&hc[1 * 512 + i * 8], a1);
                a2 = dot8h(w, *(const half8*)&hc[2 * 512 + i * 8], a2);
                a3 = dot8h(w, *(const half8*)&hc[3 * 512 + i * 8], a3);
            }
#pragma unroll 8
            for (int i = 0; i < 32; ++i) {
                half8 w = whh[(size_t)i * 1024];
                a0 = dot8h(w, *(const half8*)&hm[0 * 256 + i * 8], a0);
                a1 = dot8h(w, *(const half8*)&hm[1 * 256 + i * 8], a1);
                a2 = dot8h(w, *(const half8*)&hm[2 * 256 + i * 8], a2);
                a3 = dot8h(w, *(const half8*)&hm[3 * 256 + i * 8], a3);
            }
            gbuf[0 * 1024 + o] = a0; gbuf[1 * 1024 + o] = a1;
            gbuf[2 * 1024 + o] = a2; gbuf[3 * 1024 + o] = a3;
        }
        __syncthreads();

        // (h) mid LSTM update + store mid (c in register)
        {
            const int b = tid >> 8, k = tid & 255;
            float gi = gbuf[b * H4_ + k];
            float gf = gbuf[b * H4_ + H_ + k];
            float gg = gbuf[b * H4_ + 2 * H_ + k];
            float go = gbuf[b * H4_ + 3 * H_ + k];
            float c2 = sigm(gf) * c_mid + sigm(gi) * tanh_f(gg);
            float h2 = sigm(go) * tanh_f(c2);
            c_mid = c2;
            hm[b * 256 + k] = (hf_t)h2;
            scrB[((size_t)(b0 + b) * T_ + t) * H_ + k] = (hf_t)h2;
        }
        __syncthreads();
    }

    // ---------- udm pass: o<128 -> LDS u1, o>=128 -> scrA (nt) ----------
    {
        const int b = tid >> 8, r = tid & 255, oh = r >> 7, tt = r & 127;
        const half8* mrow = (const half8*)(scrB + ((size_t)(b0 + b) * T_ + tt) * H_);
        const half8* udw = (const half8*)(wb + W_UD);
        for (int o2 = 0; o2 < 128; ++o2) {
            const int o = oh * 128 + o2;
            const half8* ur = udw + (size_t)o * 32;
            float acc = Udb[o];
#pragma unroll 8
            for (int i = 0; i < 32; ++i) acc = dot8h(ur[i], mrow[i], acc);
            if (oh == 0)
                u1[((size_t)(b * 128) + o) * 128 + tt] = (hf_t)acc;
            else
                nt_store_h((hf_t)acc,
                           scrA + (((size_t)(b0 + b) * 128) + o2) * 128 + tt);
        }
    }
    __syncthreads();
    for (int i = tid; i < 1024; i += TB) wk[i] = 0.0f;   // zero dec hc
    __syncthreads();

    float c_dec = 0.0f;

    // ---------- Decoder ----------
    for (int s = 0; s < DS_; ++s) {
        // (a') Wd.[h;c] partials, k-quarter split
        {
            const int k = tid & 255, kq = tid >> 8;
            const half8* wWD = (const half8*)(wb + W_WD) + (size_t)(kq * 16) * 256 + k;
            float a0 = 0.f, a1 = 0.f, a2 = 0.f, a3 = 0.f;
#pragma unroll 8
            for (int i = 0; i < 16; ++i) {
                half8 w = wWD[(size_t)i * 256];
                a0 = dot8h(w, *(const half8*)&hc[0 * 512 + kq * 128 + i * 8], a0);
                a1 = dot8h(w, *(const half8*)&hc[1 * 512 + kq * 128 + i * 8], a1);
                a2 = dot8h(w, *(const half8*)&hc[2 * 512 + kq * 128 + i * 8], a2);
                a3 = dot8h(w, *(const half8*)&hc[3 * 512 + kq * 128 + i * 8], a3);
            }
            gbuf[kq * 1024 + 0 * 256 + k] = a0;
            gbuf[kq * 1024 + 1 * 256 + k] = a1;
            gbuf[kq * 1024 + 2 * 256 + k] = a2;
            gbuf[kq * 1024 + 3 * 256 + k] = a3;
        }
        __syncthreads();
        {
            const int b = tid >> 8, k = tid & 255;
            hcxi[b * 256 + k] = gbuf[b * 256 + k] + gbuf[1024 + b * 256 + k]
                              + gbuf[2048 + b * 256 + k] + gbuf[3072 + b * 256 + k]
                              + Wdb[k];
        }
        __syncthreads();

        // (b') temporal scores: kh=0 LDS u1, kh=1 HBM scrA (nt)
        {
            const int b = tid >> 8, r = tid & 255, kh = r >> 7, j = r & 127;
            const float* hx = hcxi + b * 256 + kh * 128;
            const float* vw = vds + kh * 128;
            float acc = kh ? 0.f : Vdb[0];
            if (kh == 0) {
                const hf_t* up = u1 + ((size_t)(b * 128)) * 128 + j;
#pragma unroll 8
                for (int k2 = 0; k2 < 128; ++k2) {
                    float u = (float)up[(size_t)k2 * 128];
                    acc = fmaf(vw[k2], tanh_f(hx[k2] + u), acc);
                }
            } else {
                const hf_t* up = scrA + ((size_t)(b0 + b) * 128) * 128 + j;
#pragma unroll 8
                for (int k2 = 0; k2 < 128; ++k2) {
                    float u = (float)nt_load_h(up + (size_t)k2 * 128);
                    acc = fmaf(vw[k2], tanh_f(hx[k2] + u), acc);
                }
            }
            gbuf[tid] = acc;
        }
        __syncthreads();
        if (tid < 512) {   // sbuf = gbuf[1024..1536)
            const int b = tid >> 7, j = tid & 127;
            gbuf[1024 + b * 128 + j] = gbuf[(b << 8) + j] + gbuf[(b << 8) + 128 + j];
        }
        __syncthreads();

        // (d') dec_in[b,h] = sum_j t[b,j] * mid[b,j,h]
        {
            const int b = tid >> 8, h = tid & 255;
            const hf_t* mp = scrB + (size_t)(b0 + b) * T_ * H_ + h;
            const float* sb = gbuf + 1024 + b * 128;
            float acc = 0.0f;
            for (int j = 0; j < T_; ++j)
                acc = fmaf(sb[j], (float)mp[(size_t)j * H_], acc);
            dinh[b * 256 + h] = (hf_t)acc;
        }
        __syncthreads();

        // (e') decoder gates
        {
            const int o = tid;
            const half8* wih = (const half8*)(wb + W_DWIH) + o;
            const half8* whh = (const half8*)(wb + W_DWHH) + o;
            float bias = dbih[o] + dbhh[o];
            float a0 = bias, a1 = bias, a2 = bias, a3 = bias;
#pragma unroll 8
            for (int i = 0; i < 32; ++i) {
                half8 w = wih[(size_t)i * 1024];
                a0 = dot8h(w, *(const half8*)&dinh[0 * 256 + i * 8], a0);
                a1 = dot8h(w, *(const half8*)&dinh[1 * 256 + i * 8], a1);
                a2 = dot8h(w, *(const half8*)&dinh[2 * 256 + i * 8], a2);
                a3 = dot8h(w, *(const half8*)&dinh[3 * 256 + i * 8], a3);
            }
#pragma unroll 8
            for (int i = 0; i < 32; ++i) {
                half8 w = whh[(size_t)i * 1024];
                a0 = dot8h(w, *(const half8*)&hc[0 * 512 + i * 8], a0);
                a1 = dot8h(w, *(const half8*)&hc[1 * 512 + i * 8], a1);
                a2 = dot8h(w, *(const half8*)&hc[2 * 512 + i * 8], a2);
                a3 = dot8h(w, *(const half8*)&hc[3 * 512 + i * 8], a3);
            }
            gbuf[0 * 1024 + o] = a0; gbuf[1 * 1024 + o] = a1;
            gbuf[2 * 1024 + o] = a2; gbuf[3 * 1024 + o] = a3;
        }
        __syncthreads();

        // (f') decoder LSTM update (c in register), keep h2 for (g')
        float h2dec;
        {
            const int b = tid >> 8, k = tid & 255;
            float gi = gbuf[b * H4_ + k];
            float gf = gbuf[b * H4_ + H_ + k];
            float gg = gbuf[b * H4_ + 2 * H_ + k];
            float go = gbuf[b * H4_ + 3 * H_ + k];
            float c2 = sigm(gf) * c_dec + sigm(gi) * tanh_f(gg);
            h2dec = sigm(go) * tanh_f(c2);
            c_dec = c2;
            hc[b * 512 + k]       = (hf_t)h2dec;
            hc[b * 512 + 256 + k] = (hf_t)c2;
        }
        __syncthreads();

        // (g') out[b, s-6] = rW.h + rb  (wave shuffle reduce, no hful)
        if (s >= 6) {
            const int k = tid & 255;
            float p = rW[k] * h2dec;
            for (int d = 1; d < 64; d <<= 1) p += __shfl_xor(p, d);
            if ((tid & 63) == 0) red[tid >> 6] = p;   // red[w], w = 0..15
        }
        __syncthreads();
        if (s >= 6 && tid < 4) {
            float v = red[tid * 4] + red[tid * 4 + 1]
                    + red[tid * 4 + 2] + red[tid * 4 + 3] + rb[0];
            out[(size_t)(b0 + tid) * TD_ + (s - 6)] = v;
        }
        __syncthreads();
    }
}

extern "C" void kernel_launch(void* const* d_in, const int* in_sizes, int n_in,
                              void* d_out, int out_size, void* d_ws, size_t ws_size,
                              hipStream_t stream) {
    const float* inp  = (const float*)d_in[0];
    const float* UeW  = (const float*)d_in[2];
    const float* Ueb  = (const float*)d_in[3];
    const float* Ue2W = (const float*)d_in[4];
    const float* Ue2b = (const float*)d_in[5];
    const float* WeW  = (const float*)d_in[6];
    const float* Web  = (const float*)d_in[7];
    const float* VeW  = (const float*)d_in[8];
    const float* Veb  = (const float*)d_in[9];
    const float* UdW  = (const float*)d_in[10];
    const float* Udb  = (const float*)d_in[11];
    const float* WdW  = (const float*)d_in[12];
    const float* Wdb  = (const float*)d_in[13];
    const float* VdW  = (const float*)d_in[14];
    const float* Vdb  = (const float*)d_in[15];
    const float* eWih = (const float*)d_in[16];
    const float* eWhh = (const float*)d_in[17];
    const float* ebih = (const float*)d_in[18];
    const float* ebhh = (const float*)d_in[19];
    const float* mWih = (const float*)d_in[20];
    const float* mWhh = (const float*)d_in[21];
    const float* mbih = (const float*)d_in[22];
    const float* mbhh = (const float*)d_in[23];
    const float* dWih = (const float*)d_in[24];
    const float* dWhh = (const float*)d_in[25];
    const float* dbih = (const float*)d_in[26];
    const float* dbhh = (const float*)d_in[27];
    const float* rW   = (const float*)d_in[28];
    const float* rb   = (const float*)d_in[29];

    hf_t* wsb  = (hf_t*)d_ws;
    hf_t* scrA = wsb + SCR_A;
    hf_t* scrB = wsb + SCR_B;

    // allow 160 KB dynamic LDS (one-time attribute; host-side, graph-safe)
    static bool attr_set = false;
    if (!attr_set) {
        hipFuncSetAttribute((const void*)dsrnn_kernel,
                            hipFuncAttributeMaxDynamicSharedMemorySize, LDS_BYTES);
        attr_set = true;
    }

    convw_kernel<<<512, 256, 0, stream>>>(WeW, Ue2W, eWih, eWhh, mWih, mWhh,
                                          dWih, dWhh, WdW, UdW, wsb);

    dsrnn_kernel<<<B_ / BB, TB, LDS_BYTES, stream>>>(
        inp, UeW, Ueb, Ue2b, Web, VeW, Veb, Udb, Wdb, VdW, Vdb,
        ebih, ebhh, mbih, mbhh, dbih, dbhh, rW, rb,
        wsb, scrA, scrB, (float*)d_out);
}